// Round 1
// baseline (245.696 us; speedup 1.0000x reference)
//
#include <hip/hip_runtime.h>
#include <hip/hip_fp16.h>

#define BB 32
#define SS 2048
#define FF 64
#define L2E 1.44269504088896340736f

typedef _Float16 f16x4 __attribute__((ext_vector_type(4)));
typedef _Float16 f16x8 __attribute__((ext_vector_type(8)));
typedef float f32x4 __attribute__((ext_vector_type(4)));

// ---------------- Kernel A: QKV projection ----------------
// x [B,S,64] f32 -> qp [B*S][32] f16 (d24..31 = 0), kp same, vt [B][32][S] f16
__global__ __launch_bounds__(256) void qkv_kernel(
    const float* __restrict__ x, const float* __restrict__ Wq,
    const float* __restrict__ Wk, const float* __restrict__ Wv,
    _Float16* __restrict__ qp, _Float16* __restrict__ kp,
    _Float16* __restrict__ vt)
{
    __shared__ float xs[64 * 65];    // 64 rows x 64, padded
    __shared__ float wc[64 * 96];    // combined weights: [f][96] cols: q(24)+pad8, k(24)+pad8, v(32)

    int t = threadIdx.x;
    for (int i = t; i < 64 * 96; i += 256) {
        int f = i / 96, c = i % 96;
        float v = 0.f;
        if (c < 24) v = Wq[f * 24 + c];
        else if (c >= 32 && c < 56) v = Wk[f * 24 + (c - 32)];
        else if (c >= 64) v = Wv[f * 32 + (c - 64)];
        wc[i] = v;
    }
    long rowbase = (long)blockIdx.x * 64;
    const float4* xg = (const float4*)(x + rowbase * 64);
    for (int i = t; i < 64 * 16; i += 256) {
        int r = i >> 4, c4 = i & 15;
        float4 v = xg[i];
        xs[r * 65 + c4 * 4 + 0] = v.x;
        xs[r * 65 + c4 * 4 + 1] = v.y;
        xs[r * 65 + c4 * 4 + 2] = v.z;
        xs[r * 65 + c4 * 4 + 3] = v.w;
    }
    __syncthreads();

    int rg = t >> 4;   // 16 row-groups of 4 rows
    int cg = t & 15;   // 16 col-groups of 6 cols
    float acc[4][6];
    #pragma unroll
    for (int j = 0; j < 4; ++j)
        #pragma unroll
        for (int i = 0; i < 6; ++i) acc[j][i] = 0.f;

    #pragma unroll 8
    for (int f = 0; f < 64; ++f) {
        float xv[4];
        #pragma unroll
        for (int j = 0; j < 4; ++j) xv[j] = xs[(rg * 4 + j) * 65 + f];
        #pragma unroll
        for (int i = 0; i < 6; ++i) {
            float w = wc[f * 96 + cg * 6 + i];
            #pragma unroll
            for (int j = 0; j < 4; ++j) acc[j][i] += xv[j] * w;
        }
    }

    #pragma unroll
    for (int j = 0; j < 4; ++j) {
        long R = rowbase + rg * 4 + j;
        int b = (int)(R >> 11), s = (int)(R & 2047);
        #pragma unroll
        for (int i = 0; i < 6; ++i) {
            int c = cg * 6 + i;
            _Float16 h = (_Float16)acc[j][i];
            if (c < 32) qp[R * 32 + c] = h;
            else if (c < 64) kp[R * 32 + (c - 32)] = h;
            else vt[((long)b * 32 + (c - 64)) * SS + s] = h;
        }
    }
}

// ---------------- Kernel B: column softmax stats ----------------
// wcol[b*S + k] = log2( sum_q 2^(a[q,k]*log2e) )
__global__ __launch_bounds__(256) void stats_kernel(
    const _Float16* __restrict__ qp, const _Float16* __restrict__ kp,
    float* __restrict__ wcol)
{
    int k0 = blockIdx.x * 16;
    int b = blockIdx.y;
    int t = threadIdx.x;
    int wv = t >> 6;
    int l = t & 63, llo = l & 15, lhi = l >> 4;

    f16x8 afrag = *(const f16x8*)(kp + ((long)b * SS + k0 + llo) * 32 + 8 * lhi);
    f32x4 z = {0.f, 0.f, 0.f, 0.f};
    long qbase = (long)b * SS + wv * 512;

    for (int qi = 0; qi < 32; ++qi) {
        f16x8 bfrag = *(const f16x8*)(qp + (qbase + qi * 16 + llo) * 32 + 8 * lhi);
        f32x4 d = __builtin_amdgcn_mfma_f32_16x16x32_f16(afrag, bfrag,
                    (f32x4){0.f, 0.f, 0.f, 0.f}, 0, 0, 0);
        #pragma unroll
        for (int r = 0; r < 4; ++r) z[r] += exp2f(d[r] * L2E);
    }
    // reduce over q-lanes (lane bits 0..3)
    #pragma unroll
    for (int m = 1; m < 16; m <<= 1) {
        #pragma unroll
        for (int r = 0; r < 4; ++r) z[r] += __shfl_xor(z[r], m, 64);
    }
    __shared__ float zred[4][16];
    if (llo == 0) {
        #pragma unroll
        for (int r = 0; r < 4; ++r) zred[wv][lhi * 4 + r] = z[r];
    }
    __syncthreads();
    if (t < 16) {
        float zt = zred[0][t] + zred[1][t] + zred[2][t] + zred[3][t];
        wcol[(long)b * SS + k0 + t] = log2f(zt);
    }
}

// ---------------- Kernel C: attention + output projection ----------------
__global__ __launch_bounds__(256) void attn_out_kernel(
    const _Float16* __restrict__ qp, const _Float16* __restrict__ kp,
    const _Float16* __restrict__ vt, const float* __restrict__ wcol,
    const float* __restrict__ Wh, float* __restrict__ out)
{
    __shared__ float whs[32 * 64];
    __shared__ float h1s[4][16][33];

    int t = threadIdx.x;
    for (int i = t; i < 2048; i += 256) whs[i] = Wh[i];

    int b = blockIdx.y;
    int wv = t >> 6, l = t & 63, llo = l & 15, lhi = l >> 4;
    int q0 = blockIdx.x * 64 + wv * 16;

    f16x8 qfrag = *(const f16x8*)(qp + ((long)b * SS + q0 + llo) * 32 + 8 * lhi);
    f32x4 acc0 = {0.f, 0.f, 0.f, 0.f}, acc1 = {0.f, 0.f, 0.f, 0.f};
    const float* wcb = wcol + (long)b * SS;
    const _Float16* vb0 = vt + ((long)b * 32 + llo) * SS;
    const _Float16* vb1 = vt + ((long)b * 32 + 16 + llo) * SS;
    const _Float16* kb = kp + (long)b * SS * 32 + llo * 32 + 8 * lhi;

    for (int kt = 0; kt < 128; ++kt) {
        int k0 = kt * 16;
        f16x8 kfrag = *(const f16x8*)(kb + (long)k0 * 32);
        f32x4 d = __builtin_amdgcn_mfma_f32_16x16x32_f16(kfrag, qfrag,
                    (f32x4){0.f, 0.f, 0.f, 0.f}, 0, 0, 0);
        float4 w4 = *(const float4*)(wcb + k0 + lhi * 4);
        f16x4 pa;
        pa[0] = (_Float16)exp2f(d[0] * L2E - w4.x);
        pa[1] = (_Float16)exp2f(d[1] * L2E - w4.y);
        pa[2] = (_Float16)exp2f(d[2] * L2E - w4.z);
        pa[3] = (_Float16)exp2f(d[3] * L2E - w4.w);

        f16x4 vf0 = *(const f16x4*)(vb0 + k0 + lhi * 4);
        f16x4 vf1 = *(const f16x4*)(vb1 + k0 + lhi * 4);
        acc0 = __builtin_amdgcn_mfma_f32_16x16x16f16(pa, vf0, acc0, 0, 0, 0);
        acc1 = __builtin_amdgcn_mfma_f32_16x16x16f16(pa, vf1, acc1, 0, 0, 0);
    }

    // h1 tile -> LDS  (lane holds h1[q0 + lhi*4+r, vd = llo / 16+llo])
    #pragma unroll
    for (int r = 0; r < 4; ++r) {
        h1s[wv][lhi * 4 + r][llo] = acc0[r];
        h1s[wv][lhi * 4 + r][16 + llo] = acc1[r];
    }
    __syncthreads();

    const float* h1w = &h1s[wv][0][0];
    long obase = ((long)b * SS + q0) * 64;
    for (int j = 0; j < 16; ++j) {
        float a = 0.f;
        #pragma unroll
        for (int vd = 0; vd < 32; ++vd) a += h1w[j * 33 + vd] * whs[vd * 64 + l];
        out[obase + (long)j * 64 + l] = a;
    }
}

extern "C" void kernel_launch(void* const* d_in, const int* in_sizes, int n_in,
                              void* d_out, int out_size, void* d_ws, size_t ws_size,
                              hipStream_t stream) {
    const float* x  = (const float*)d_in[0];
    const float* Wq = (const float*)d_in[1];
    const float* Wk = (const float*)d_in[2];
    const float* Wv = (const float*)d_in[3];
    const float* Wh = (const float*)d_in[4];
    float* out = (float*)d_out;

    char* ws = (char*)d_ws;
    _Float16* qp = (_Float16*)(ws);                       // 4 MB
    _Float16* kp = (_Float16*)(ws + (4l << 20));          // 4 MB
    _Float16* vt = (_Float16*)(ws + (8l << 20));          // 4 MB
    float* wcol  = (float*)(ws + (12l << 20));            // 256 KB

    qkv_kernel<<<dim3(1024), 256, 0, stream>>>(x, Wq, Wk, Wv, qp, kp, vt);
    stats_kernel<<<dim3(128, 32), 256, 0, stream>>>(qp, kp, wcol);
    attn_out_kernel<<<dim3(32, 32), 256, 0, stream>>>(qp, kp, vt, wcol, Wh, out);
}

// Round 2
// 165.361 us; speedup vs baseline: 1.4858x; 1.4858x over previous
//
#include <hip/hip_runtime.h>
#include <hip/hip_fp16.h>

#define BB 32
#define SS 2048
#define FF 64
#define L2E 1.44269504088896340736f

typedef _Float16 f16x4 __attribute__((ext_vector_type(4)));
typedef _Float16 f16x8 __attribute__((ext_vector_type(8)));
typedef float f32x4 __attribute__((ext_vector_type(4)));

// ---------------- Kernel A: QKV projection ----------------
// x [B,S,64] f32 -> qp [B*S][32] f16 scaled by log2e (d24..31 = 0),
// kp [B*S][32] f16, vt [B][32][S] f16
__global__ __launch_bounds__(256) void qkv_kernel(
    const float* __restrict__ x, const float* __restrict__ Wq,
    const float* __restrict__ Wk, const float* __restrict__ Wv,
    _Float16* __restrict__ qp, _Float16* __restrict__ kp,
    _Float16* __restrict__ vt)
{
    __shared__ float xs[64 * 65];    // 64 rows x 64, padded
    __shared__ float wc[64 * 96];    // [f][96]: q(24)+pad8, k(24)+pad8, v(32)

    int t = threadIdx.x;
    for (int i = t; i < 64 * 96; i += 256) {
        int f = i / 96, c = i % 96;
        float v = 0.f;
        if (c < 24) v = Wq[f * 24 + c];
        else if (c >= 32 && c < 56) v = Wk[f * 24 + (c - 32)];
        else if (c >= 64) v = Wv[f * 32 + (c - 64)];
        wc[i] = v;
    }
    long rowbase = (long)blockIdx.x * 64;
    const float4* xg = (const float4*)(x + rowbase * 64);
    for (int i = t; i < 64 * 16; i += 256) {
        int r = i >> 4, c4 = i & 15;
        float4 v = xg[i];
        xs[r * 65 + c4 * 4 + 0] = v.x;
        xs[r * 65 + c4 * 4 + 1] = v.y;
        xs[r * 65 + c4 * 4 + 2] = v.z;
        xs[r * 65 + c4 * 4 + 3] = v.w;
    }
    __syncthreads();

    int rg = t >> 4;   // 16 row-groups of 4 rows
    int cg = t & 15;   // 16 col-groups of 6 cols
    float acc[4][6];
    #pragma unroll
    for (int j = 0; j < 4; ++j)
        #pragma unroll
        for (int i = 0; i < 6; ++i) acc[j][i] = 0.f;

    #pragma unroll 8
    for (int f = 0; f < 64; ++f) {
        float xv[4];
        #pragma unroll
        for (int j = 0; j < 4; ++j) xv[j] = xs[(rg * 4 + j) * 65 + f];
        #pragma unroll
        for (int i = 0; i < 6; ++i) {
            float w = wc[f * 96 + cg * 6 + i];
            #pragma unroll
            for (int j = 0; j < 4; ++j) acc[j][i] += xv[j] * w;
        }
    }

    #pragma unroll
    for (int j = 0; j < 4; ++j) {
        long R = rowbase + rg * 4 + j;
        int b = (int)(R >> 11), s = (int)(R & 2047);
        #pragma unroll
        for (int i = 0; i < 6; ++i) {
            int c = cg * 6 + i;
            if (c < 32) qp[R * 32 + c] = (_Float16)(acc[j][i] * L2E);
            else if (c < 64) kp[R * 32 + (c - 32)] = (_Float16)acc[j][i];
            else vt[((long)b * 32 + (c - 64)) * SS + s] = (_Float16)acc[j][i];
        }
    }
}

// ---------------- Kernel B: column softmax stats ----------------
// wcol[b*S + k] = log2( sum_q 2^(score_log2[q,k]) )   (qp pre-scaled by log2e)
__global__ __launch_bounds__(256) void stats_kernel(
    const _Float16* __restrict__ qp, const _Float16* __restrict__ kp,
    float* __restrict__ wcol)
{
    int k0 = blockIdx.x * 16;
    int b = blockIdx.y;
    int t = threadIdx.x;
    int wv = t >> 6;
    int l = t & 63, llo = l & 15, lhi = l >> 4;

    // A-frag: K rows k0+llo, feature slice 8*lhi
    f16x8 afrag = *(const f16x8*)(kp + ((long)b * SS + k0 + llo) * 32 + 8 * lhi);
    f32x4 z = {0.f, 0.f, 0.f, 0.f};
    const _Float16* qb = qp + ((long)b * SS + wv * 512 + llo) * 32 + 8 * lhi;

    #pragma unroll 2
    for (int qi = 0; qi < 16; ++qi) {
        f16x8 b0 = *(const f16x8*)(qb + (long)(qi * 32) * 32);
        f16x8 b1 = *(const f16x8*)(qb + (long)(qi * 32 + 16) * 32);
        f32x4 d0 = __builtin_amdgcn_mfma_f32_16x16x32_f16(afrag, b0,
                     (f32x4){0.f, 0.f, 0.f, 0.f}, 0, 0, 0);
        f32x4 d1 = __builtin_amdgcn_mfma_f32_16x16x32_f16(afrag, b1,
                     (f32x4){0.f, 0.f, 0.f, 0.f}, 0, 0, 0);
        #pragma unroll
        for (int r = 0; r < 4; ++r) z[r] += exp2f(d0[r]) + exp2f(d1[r]);
    }
    // sum over q (lane bits 0..3 = llo)
    #pragma unroll
    for (int m = 1; m < 16; m <<= 1) {
        #pragma unroll
        for (int r = 0; r < 4; ++r) z[r] += __shfl_xor(z[r], m, 64);
    }
    __shared__ float zred[4][16];
    if (llo == 0) {
        #pragma unroll
        for (int r = 0; r < 4; ++r) zred[wv][lhi * 4 + r] = z[r];
    }
    __syncthreads();
    if (t < 16) {
        float zt = zred[0][t] + zred[1][t] + zred[2][t] + zred[3][t];
        wcol[(long)b * SS + k0 + t] = log2f(zt);
    }
}

// ---------------- Kernel C: attention + output projection ----------------
// 4 waves/block; each wave: 32 q-rows (2 q-frags); block: 128 q-rows.
__global__ __launch_bounds__(256) void attn_out_kernel(
    const _Float16* __restrict__ qp, const _Float16* __restrict__ kp,
    const _Float16* __restrict__ vt, const float* __restrict__ wcol,
    const float* __restrict__ Wh, float* __restrict__ out)
{
    __shared__ float whs[32 * 64];
    __shared__ float h1s[4][32][33];

    int t = threadIdx.x;
    for (int i = t; i < 2048; i += 256) whs[i] = Wh[i];

    int b = blockIdx.y;
    int wv = t >> 6, l = t & 63, llo = l & 15, lhi = l >> 4;
    int q0 = blockIdx.x * 128 + wv * 32;

    const _Float16* qb = qp + ((long)b * SS + q0 + llo) * 32 + 8 * lhi;
    f16x8 qf0 = *(const f16x8*)(qb);
    f16x8 qf1 = *(const f16x8*)(qb + 16 * 32);
    f32x4 acc00 = {0,0,0,0}, acc01 = {0,0,0,0};
    f32x4 acc10 = {0,0,0,0}, acc11 = {0,0,0,0};
    const float* wcb = wcol + (long)b * SS + lhi * 4;
    const _Float16* vb0 = vt + ((long)b * 32 + llo) * SS + lhi * 4;
    const _Float16* vb1 = vb0 + 16 * SS;
    const _Float16* kb = kp + (long)b * SS * 32 + llo * 32 + 8 * lhi;

    #pragma unroll 2
    for (int kt = 0; kt < 64; ++kt) {
        int k0 = kt * 32;
        f16x8 kfA = *(const f16x8*)(kb + (long)k0 * 32);
        f16x8 kfB = *(const f16x8*)(kb + (long)(k0 + 16) * 32);
        float4 wA = *(const float4*)(wcb + k0);
        float4 wB = *(const float4*)(wcb + k0 + 16);
        f16x4 vA0 = *(const f16x4*)(vb0 + k0);
        f16x4 vA1 = *(const f16x4*)(vb1 + k0);
        f16x4 vB0 = *(const f16x4*)(vb0 + k0 + 16);
        f16x4 vB1 = *(const f16x4*)(vb1 + k0 + 16);

        f32x4 dA0 = __builtin_amdgcn_mfma_f32_16x16x32_f16(kfA, qf0,
                      (f32x4){0,0,0,0}, 0, 0, 0);
        f32x4 dA1 = __builtin_amdgcn_mfma_f32_16x16x32_f16(kfA, qf1,
                      (f32x4){0,0,0,0}, 0, 0, 0);
        f32x4 dB0 = __builtin_amdgcn_mfma_f32_16x16x32_f16(kfB, qf0,
                      (f32x4){0,0,0,0}, 0, 0, 0);
        f32x4 dB1 = __builtin_amdgcn_mfma_f32_16x16x32_f16(kfB, qf1,
                      (f32x4){0,0,0,0}, 0, 0, 0);

        f16x4 paA0, paA1, paB0, paB1;
        paA0[0] = (_Float16)exp2f(dA0[0] - wA.x);
        paA0[1] = (_Float16)exp2f(dA0[1] - wA.y);
        paA0[2] = (_Float16)exp2f(dA0[2] - wA.z);
        paA0[3] = (_Float16)exp2f(dA0[3] - wA.w);
        paA1[0] = (_Float16)exp2f(dA1[0] - wA.x);
        paA1[1] = (_Float16)exp2f(dA1[1] - wA.y);
        paA1[2] = (_Float16)exp2f(dA1[2] - wA.z);
        paA1[3] = (_Float16)exp2f(dA1[3] - wA.w);
        paB0[0] = (_Float16)exp2f(dB0[0] - wB.x);
        paB0[1] = (_Float16)exp2f(dB0[1] - wB.y);
        paB0[2] = (_Float16)exp2f(dB0[2] - wB.z);
        paB0[3] = (_Float16)exp2f(dB0[3] - wB.w);
        paB1[0] = (_Float16)exp2f(dB1[0] - wB.x);
        paB1[1] = (_Float16)exp2f(dB1[1] - wB.y);
        paB1[2] = (_Float16)exp2f(dB1[2] - wB.z);
        paB1[3] = (_Float16)exp2f(dB1[3] - wB.w);

        acc00 = __builtin_amdgcn_mfma_f32_16x16x16f16(paA0, vA0, acc00, 0, 0, 0);
        acc01 = __builtin_amdgcn_mfma_f32_16x16x16f16(paA0, vA1, acc01, 0, 0, 0);
        acc10 = __builtin_amdgcn_mfma_f32_16x16x16f16(paA1, vA0, acc10, 0, 0, 0);
        acc11 = __builtin_amdgcn_mfma_f32_16x16x16f16(paA1, vA1, acc11, 0, 0, 0);
        acc00 = __builtin_amdgcn_mfma_f32_16x16x16f16(paB0, vB0, acc00, 0, 0, 0);
        acc01 = __builtin_amdgcn_mfma_f32_16x16x16f16(paB0, vB1, acc01, 0, 0, 0);
        acc10 = __builtin_amdgcn_mfma_f32_16x16x16f16(paB1, vB0, acc10, 0, 0, 0);
        acc11 = __builtin_amdgcn_mfma_f32_16x16x16f16(paB1, vB1, acc11, 0, 0, 0);
    }

    // h1 tile -> LDS (wave-private region)
    #pragma unroll
    for (int r = 0; r < 4; ++r) {
        h1s[wv][lhi * 4 + r][llo]           = acc00[r];
        h1s[wv][lhi * 4 + r][16 + llo]      = acc01[r];
        h1s[wv][16 + lhi * 4 + r][llo]      = acc10[r];
        h1s[wv][16 + lhi * 4 + r][16 + llo] = acc11[r];
    }
    __syncthreads();   // also covers whs fill

    const float* h1w = &h1s[wv][0][0];
    long obase = ((long)b * SS + q0) * 64;
    for (int j = 0; j < 32; ++j) {
        float a = 0.f;
        #pragma unroll
        for (int vd = 0; vd < 32; ++vd) a += h1w[j * 33 + vd] * whs[vd * 64 + l];
        out[obase + (long)j * 64 + l] = a;
    }
}

extern "C" void kernel_launch(void* const* d_in, const int* in_sizes, int n_in,
                              void* d_out, int out_size, void* d_ws, size_t ws_size,
                              hipStream_t stream) {
    const float* x  = (const float*)d_in[0];
    const float* Wq = (const float*)d_in[1];
    const float* Wk = (const float*)d_in[2];
    const float* Wv = (const float*)d_in[3];
    const float* Wh = (const float*)d_in[4];
    float* out = (float*)d_out;

    char* ws = (char*)d_ws;
    _Float16* qp = (_Float16*)(ws);                       // 4 MB
    _Float16* kp = (_Float16*)(ws + (4l << 20));          // 4 MB
    _Float16* vt = (_Float16*)(ws + (8l << 20));          // 4 MB
    float* wcol  = (float*)(ws + (12l << 20));            // 256 KB

    qkv_kernel<<<dim3(1024), 256, 0, stream>>>(x, Wq, Wk, Wv, qp, kp, vt);
    stats_kernel<<<dim3(128, 32), 256, 0, stream>>>(qp, kp, wcol);
    attn_out_kernel<<<dim3(16, 32), 256, 0, stream>>>(qp, kp, vt, wcol, Wh, out);
}

// Round 3
// 152.846 us; speedup vs baseline: 1.6075x; 1.0819x over previous
//
#include <hip/hip_runtime.h>
#include <hip/hip_fp16.h>

#define SS 2048
#define L2E 1.44269504088896340736f

typedef _Float16 f16x4 __attribute__((ext_vector_type(4)));
typedef _Float16 f16x8 __attribute__((ext_vector_type(8)));
typedef float f32x4 __attribute__((ext_vector_type(4)));

// ---------------- Kernel A: QKV projection ----------------
// x [B,S,64] f32 -> qp [B*S][32] f16 scaled by log2e (cols 24..31 = 0),
// kp [B*S][32] f16, vt [B][32][S] f16
__global__ __launch_bounds__(256) void qkv_kernel(
    const float* __restrict__ x, const float* __restrict__ Wq,
    const float* __restrict__ Wk, const float* __restrict__ Wv,
    _Float16* __restrict__ qp, _Float16* __restrict__ kp,
    _Float16* __restrict__ vt)
{
    __shared__ float xs[64 * 65];    // 64 rows x 64, padded
    __shared__ float wc[64 * 96];    // [f][96]: q(24)+pad8, k(24)+pad8, v(32)

    int t = threadIdx.x;
    for (int i = t; i < 64 * 96; i += 256) {
        int f = i / 96, c = i % 96;
        float v = 0.f;
        if (c < 24) v = Wq[f * 24 + c];
        else if (c >= 32 && c < 56) v = Wk[f * 24 + (c - 32)];
        else if (c >= 64) v = Wv[f * 32 + (c - 64)];
        wc[i] = v;
    }
    long rowbase = (long)blockIdx.x * 64;
    const float4* xg = (const float4*)(x + rowbase * 64);
    for (int i = t; i < 64 * 16; i += 256) {
        int r = i >> 4, c4 = i & 15;
        float4 v = xg[i];
        xs[r * 65 + c4 * 4 + 0] = v.x;
        xs[r * 65 + c4 * 4 + 1] = v.y;
        xs[r * 65 + c4 * 4 + 2] = v.z;
        xs[r * 65 + c4 * 4 + 3] = v.w;
    }
    __syncthreads();

    int rg = t >> 4;   // 16 row-groups of 4 rows
    int cg = t & 15;   // 16 col-groups of 6 cols
    float acc[4][6];
    #pragma unroll
    for (int j = 0; j < 4; ++j)
        #pragma unroll
        for (int i = 0; i < 6; ++i) acc[j][i] = 0.f;

    #pragma unroll 8
    for (int f = 0; f < 64; ++f) {
        float xv[4];
        #pragma unroll
        for (int j = 0; j < 4; ++j) xv[j] = xs[(rg * 4 + j) * 65 + f];
        #pragma unroll
        for (int i = 0; i < 6; ++i) {
            float w = wc[f * 96 + cg * 6 + i];
            #pragma unroll
            for (int j = 0; j < 4; ++j) acc[j][i] += xv[j] * w;
        }
    }

    #pragma unroll
    for (int j = 0; j < 4; ++j) {
        long R = rowbase + rg * 4 + j;
        int b = (int)(R >> 11), s = (int)(R & 2047);
        #pragma unroll
        for (int i = 0; i < 6; ++i) {
            int c = cg * 6 + i;
            if (c < 32) qp[R * 32 + c] = (_Float16)(acc[j][i] * L2E);
            else if (c < 64) kp[R * 32 + (c - 32)] = (_Float16)acc[j][i];
            else vt[((long)b * 32 + (c - 64)) * SS + s] = (_Float16)acc[j][i];
        }
    }
}

// ---------------- Kernel B: column softmax stats ----------------
// wneg[b*S + k] = -log2( sum_q 2^(score_log2[q,k]) )   (qp pre-scaled by log2e)
// Each wave owns 16 k (hoisted A-frag) and streams all 2048 q with
// register-prefetched loads. No LDS, no barriers.
__global__ __launch_bounds__(256) void stats_kernel(
    const _Float16* __restrict__ qp, const _Float16* __restrict__ kp,
    float* __restrict__ wneg)
{
    int b = blockIdx.y;
    int t = threadIdx.x;
    int wv = t >> 6, l = t & 63, llo = l & 15, lhi = l >> 4;
    int kbase = blockIdx.x * 64 + wv * 16;

    f16x8 afrag = *(const f16x8*)(kp + ((long)b * SS + kbase + llo) * 32 + 8 * lhi);
    const _Float16* qb = qp + ((long)b * SS + llo) * 32 + 8 * lhi;

    f32x4 z0 = {0,0,0,0}, z1 = {0,0,0,0};
    f16x8 c0 = *(const f16x8*)(qb);
    f16x8 c1 = *(const f16x8*)(qb + 512);

    #pragma unroll 2
    for (int qt = 0; qt < 64; ++qt) {
        int qn = (qt + 1) & 63;
        f16x8 n0 = *(const f16x8*)(qb + qn * 1024);
        f16x8 n1 = *(const f16x8*)(qb + qn * 1024 + 512);
        __builtin_amdgcn_s_setprio(1);
        f32x4 d0 = __builtin_amdgcn_mfma_f32_16x16x32_f16(afrag, c0,
                     (f32x4){0,0,0,0}, 0, 0, 0);
        f32x4 d1 = __builtin_amdgcn_mfma_f32_16x16x32_f16(afrag, c1,
                     (f32x4){0,0,0,0}, 0, 0, 0);
        __builtin_amdgcn_s_setprio(0);
        #pragma unroll
        for (int r = 0; r < 4; ++r) {
            z0[r] += __builtin_amdgcn_exp2f(d0[r]);
            z1[r] += __builtin_amdgcn_exp2f(d1[r]);
        }
        c0 = n0; c1 = n1;
    }
    #pragma unroll
    for (int r = 0; r < 4; ++r) z0[r] += z1[r];
    // sum over the 16 q-lanes (lane bits 0..3)
    #pragma unroll
    for (int m = 1; m < 16; m <<= 1)
        #pragma unroll
        for (int r = 0; r < 4; ++r) z0[r] += __shfl_xor(z0[r], m, 64);
    if (llo == 0) {
        #pragma unroll
        for (int r = 0; r < 4; ++r)
            wneg[(long)b * SS + kbase + lhi * 4 + r] = -__builtin_amdgcn_logf(z0[r]);
    }
}

// ---------------- Kernel C: attention + output projection ----------------
// 4 waves/block, 32 q-rows/wave, zero LDS. Swapped PV (mfma(V,P)) puts h1^T
// in B-fragment layout so the 32->64 projection is done with MFMA directly.
__global__ __launch_bounds__(256) void attn_out_kernel(
    const _Float16* __restrict__ qp, const _Float16* __restrict__ kp,
    const _Float16* __restrict__ vt, const float* __restrict__ wneg,
    const float* __restrict__ Wh, float* __restrict__ out)
{
    int b = blockIdx.y;
    int t = threadIdx.x;
    int wv = t >> 6, l = t & 63, llo = l & 15, lhi = l >> 4;
    int q0 = blockIdx.x * 128 + wv * 32;

    const _Float16* qb = qp + ((long)b * SS + q0 + llo) * 32 + 8 * lhi;
    f16x8 qf0 = *(const f16x8*)(qb);
    f16x8 qf1 = *(const f16x8*)(qb + 512);

    // Wh^T A-fragments for the epilogue: whlo[fb][j] = Wh[vd=4*lhi+j][fb*16+llo]
    f16x4 whlo[4], whhi[4];
    #pragma unroll
    for (int fb = 0; fb < 4; ++fb) {
        #pragma unroll
        for (int j = 0; j < 4; ++j) {
            whlo[fb][j] = (_Float16)Wh[(4 * lhi + j) * 64 + fb * 16 + llo];
            whhi[fb][j] = (_Float16)Wh[(16 + 4 * lhi + j) * 64 + fb * 16 + llo];
        }
    }

    f32x4 aV0Q0 = {0,0,0,0}, aV1Q0 = {0,0,0,0};
    f32x4 aV0Q1 = {0,0,0,0}, aV1Q1 = {0,0,0,0};
    const float* wcb = wneg + (long)b * SS + lhi * 4;
    const _Float16* vb0 = vt + ((long)b * 32 + llo) * SS + lhi * 4;
    const _Float16* vb1 = vb0 + 16 * SS;
    const _Float16* kb = kp + (long)b * SS * 32 + llo * 32 + 8 * lhi;

    struct Tile {
        f16x8 kfA, kfB;
        float4 wA, wB;
        f16x4 vA0, vA1, vB0, vB1;
    };
    auto load_tile = [&](Tile& T, int k0) {
        T.kfA = *(const f16x8*)(kb + (long)k0 * 32);
        T.kfB = *(const f16x8*)(kb + (long)(k0 + 16) * 32);
        T.wA  = *(const float4*)(wcb + k0);
        T.wB  = *(const float4*)(wcb + k0 + 16);
        T.vA0 = *(const f16x4*)(vb0 + k0);
        T.vA1 = *(const f16x4*)(vb1 + k0);
        T.vB0 = *(const f16x4*)(vb0 + k0 + 16);
        T.vB1 = *(const f16x4*)(vb1 + k0 + 16);
    };

    Tile cur, nxt;
    load_tile(cur, 0);

    #pragma unroll 2
    for (int kt = 0; kt < 64; ++kt) {
        load_tile(nxt, ((kt + 1) & 63) * 32);

        // C-init = -log2(z): softmax offset folded into the MFMA accumulator
        f32x4 cA = {cur.wA.x, cur.wA.y, cur.wA.z, cur.wA.w};
        f32x4 cB = {cur.wB.x, cur.wB.y, cur.wB.z, cur.wB.w};
        __builtin_amdgcn_s_setprio(1);
        f32x4 dA0 = __builtin_amdgcn_mfma_f32_16x16x32_f16(cur.kfA, qf0, cA, 0, 0, 0);
        f32x4 dA1 = __builtin_amdgcn_mfma_f32_16x16x32_f16(cur.kfA, qf1, cA, 0, 0, 0);
        f32x4 dB0 = __builtin_amdgcn_mfma_f32_16x16x32_f16(cur.kfB, qf0, cB, 0, 0, 0);
        f32x4 dB1 = __builtin_amdgcn_mfma_f32_16x16x32_f16(cur.kfB, qf1, cB, 0, 0, 0);
        __builtin_amdgcn_s_setprio(0);

        f16x4 paA0, paA1, paB0, paB1;
        #pragma unroll
        for (int r = 0; r < 4; ++r) {
            paA0[r] = (_Float16)__builtin_amdgcn_exp2f(dA0[r]);
            paA1[r] = (_Float16)__builtin_amdgcn_exp2f(dA1[r]);
            paB0[r] = (_Float16)__builtin_amdgcn_exp2f(dB0[r]);
            paB1[r] = (_Float16)__builtin_amdgcn_exp2f(dB1[r]);
        }

        __builtin_amdgcn_s_setprio(1);
        aV0Q0 = __builtin_amdgcn_mfma_f32_16x16x16f16(cur.vA0, paA0, aV0Q0, 0, 0, 0);
        aV1Q0 = __builtin_amdgcn_mfma_f32_16x16x16f16(cur.vA1, paA0, aV1Q0, 0, 0, 0);
        aV0Q1 = __builtin_amdgcn_mfma_f32_16x16x16f16(cur.vA0, paA1, aV0Q1, 0, 0, 0);
        aV1Q1 = __builtin_amdgcn_mfma_f32_16x16x16f16(cur.vA1, paA1, aV1Q1, 0, 0, 0);
        aV0Q0 = __builtin_amdgcn_mfma_f32_16x16x16f16(cur.vB0, paB0, aV0Q0, 0, 0, 0);
        aV1Q0 = __builtin_amdgcn_mfma_f32_16x16x16f16(cur.vB1, paB0, aV1Q0, 0, 0, 0);
        aV0Q1 = __builtin_amdgcn_mfma_f32_16x16x16f16(cur.vB0, paB1, aV0Q1, 0, 0, 0);
        aV1Q1 = __builtin_amdgcn_mfma_f32_16x16x16f16(cur.vB1, paB1, aV1Q1, 0, 0, 0);
        __builtin_amdgcn_s_setprio(0);

        cur = nxt;
    }

    // Epilogue: O^T = Wh^T * h1^T via MFMA; h1 accs are already B-fragments.
    #pragma unroll
    for (int g = 0; g < 2; ++g) {
        f32x4 hv0 = g ? aV0Q1 : aV0Q0;
        f32x4 hv1 = g ? aV1Q1 : aV1Q0;
        f16x4 h0, h1;
        #pragma unroll
        for (int r = 0; r < 4; ++r) {
            h0[r] = (_Float16)hv0[r];
            h1[r] = (_Float16)hv1[r];
        }
        int qrow = q0 + g * 16 + llo;
        float* orow = out + ((long)b * SS + qrow) * 64 + 4 * lhi;
        #pragma unroll
        for (int fb = 0; fb < 4; ++fb) {
            f32x4 o = __builtin_amdgcn_mfma_f32_16x16x16f16(whlo[fb], h0,
                        (f32x4){0,0,0,0}, 0, 0, 0);
            o = __builtin_amdgcn_mfma_f32_16x16x16f16(whhi[fb], h1, o, 0, 0, 0);
            *(f32x4*)(orow + fb * 16) = o;
        }
    }
}

extern "C" void kernel_launch(void* const* d_in, const int* in_sizes, int n_in,
                              void* d_out, int out_size, void* d_ws, size_t ws_size,
                              hipStream_t stream) {
    const float* x  = (const float*)d_in[0];
    const float* Wq = (const float*)d_in[1];
    const float* Wk = (const float*)d_in[2];
    const float* Wv = (const float*)d_in[3];
    const float* Wh = (const float*)d_in[4];
    float* out = (float*)d_out;

    char* ws = (char*)d_ws;
    _Float16* qp = (_Float16*)(ws);                       // 4 MB
    _Float16* kp = (_Float16*)(ws + (4l << 20));          // 4 MB
    _Float16* vt = (_Float16*)(ws + (8l << 20));          // 4 MB
    float* wneg  = (float*)(ws + (12l << 20));            // 256 KB

    qkv_kernel<<<dim3(1024), 256, 0, stream>>>(x, Wq, Wk, Wv, qp, kp, vt);
    stats_kernel<<<dim3(32, 32), 256, 0, stream>>>(qp, kp, wneg);
    attn_out_kernel<<<dim3(16, 32), 256, 0, stream>>>(qp, kp, vt, wneg, Wh, out);
}

// Round 4
// 111.664 us; speedup vs baseline: 2.2003x; 1.3688x over previous
//
#include <hip/hip_runtime.h>
#include <hip/hip_fp16.h>

#define SS 2048
#define L2E 1.44269504088896340736f

typedef _Float16 f16x4 __attribute__((ext_vector_type(4)));
typedef _Float16 f16x8 __attribute__((ext_vector_type(8)));
typedef float f32x4 __attribute__((ext_vector_type(4)));

// ---------------- Kernel A: QKV projection ----------------
// x [B,S,64] f32 -> qp [B*S][32] f16 scaled by log2e (cols 24..31 = 0),
// kp [B*S][32] f16, vt [B][32][S] f16
__global__ __launch_bounds__(256) void qkv_kernel(
    const float* __restrict__ x, const float* __restrict__ Wq,
    const float* __restrict__ Wk, const float* __restrict__ Wv,
    _Float16* __restrict__ qp, _Float16* __restrict__ kp,
    _Float16* __restrict__ vt)
{
    __shared__ float xs[64 * 65];
    __shared__ float wc[64 * 96];

    int t = threadIdx.x;
    for (int i = t; i < 64 * 96; i += 256) {
        int f = i / 96, c = i % 96;
        float v = 0.f;
        if (c < 24) v = Wq[f * 24 + c];
        else if (c >= 32 && c < 56) v = Wk[f * 24 + (c - 32)];
        else if (c >= 64) v = Wv[f * 32 + (c - 64)];
        wc[i] = v;
    }
    long rowbase = (long)blockIdx.x * 64;
    const float4* xg = (const float4*)(x + rowbase * 64);
    for (int i = t; i < 64 * 16; i += 256) {
        int r = i >> 4, c4 = i & 15;
        float4 v = xg[i];
        xs[r * 65 + c4 * 4 + 0] = v.x;
        xs[r * 65 + c4 * 4 + 1] = v.y;
        xs[r * 65 + c4 * 4 + 2] = v.z;
        xs[r * 65 + c4 * 4 + 3] = v.w;
    }
    __syncthreads();

    int rg = t >> 4;
    int cg = t & 15;
    float acc[4][6];
    #pragma unroll
    for (int j = 0; j < 4; ++j)
        #pragma unroll
        for (int i = 0; i < 6; ++i) acc[j][i] = 0.f;

    #pragma unroll 8
    for (int f = 0; f < 64; ++f) {
        float xv[4];
        #pragma unroll
        for (int j = 0; j < 4; ++j) xv[j] = xs[(rg * 4 + j) * 65 + f];
        #pragma unroll
        for (int i = 0; i < 6; ++i) {
            float w = wc[f * 96 + cg * 6 + i];
            #pragma unroll
            for (int j = 0; j < 4; ++j) acc[j][i] += xv[j] * w;
        }
    }

    #pragma unroll
    for (int j = 0; j < 4; ++j) {
        long R = rowbase + rg * 4 + j;
        int b = (int)(R >> 11), s = (int)(R & 2047);
        #pragma unroll
        for (int i = 0; i < 6; ++i) {
            int c = cg * 6 + i;
            if (c < 32) qp[R * 32 + c] = (_Float16)(acc[j][i] * L2E);
            else if (c < 64) kp[R * 32 + (c - 32)] = (_Float16)acc[j][i];
            else vt[((long)b * 32 + (c - 64)) * SS + s] = (_Float16)acc[j][i];
        }
    }
}

// ---------------- Kernel B: partial column-softmax sums ----------------
// Wave owns 64 k (4 hoisted K-frags), streams 256 q (8 iters x 32 q).
// zpart[qs][b][k] = sum over that q-slice of 2^score.
__global__ __launch_bounds__(256) void stats_kernel(
    const _Float16* __restrict__ qp, const _Float16* __restrict__ kp,
    float* __restrict__ zpart)
{
    int w = blockIdx.x;
    int b = (w & 7) * 4 + ((w >> 3) & 3);   // same-b blocks share XCD residue
    int rest = w >> 5;                       // 0..63
    int kb = rest >> 3, qs = rest & 7;
    int t = threadIdx.x;
    int wv = t >> 6, l = t & 63, llo = l & 15, lhi = l >> 4;
    int kbase = kb * 256 + wv * 64;

    f16x8 af[4];
    #pragma unroll
    for (int kt = 0; kt < 4; ++kt)
        af[kt] = *(const f16x8*)(kp + ((long)b * SS + kbase + kt * 16 + llo) * 32 + 8 * lhi);

    const _Float16* qb = qp + ((long)b * SS + qs * 256 + llo) * 32 + 8 * lhi;
    f32x4 z[4] = {{0,0,0,0},{0,0,0,0},{0,0,0,0},{0,0,0,0}};
    f16x8 c0 = *(const f16x8*)(qb);
    f16x8 c1 = *(const f16x8*)(qb + 512);

    #pragma unroll 2
    for (int qi = 0; qi < 8; ++qi) {
        int qn = (qi + 1) & 7;
        f16x8 n0 = *(const f16x8*)(qb + qn * 1024);
        f16x8 n1 = *(const f16x8*)(qb + qn * 1024 + 512);
        #pragma unroll
        for (int kt = 0; kt < 4; ++kt) {
            f32x4 d0 = __builtin_amdgcn_mfma_f32_16x16x32_f16(af[kt], c0,
                         (f32x4){0,0,0,0}, 0, 0, 0);
            f32x4 d1 = __builtin_amdgcn_mfma_f32_16x16x32_f16(af[kt], c1,
                         (f32x4){0,0,0,0}, 0, 0, 0);
            #pragma unroll
            for (int r = 0; r < 4; ++r)
                z[kt][r] += __builtin_amdgcn_exp2f(d0[r]) + __builtin_amdgcn_exp2f(d1[r]);
        }
        c0 = n0; c1 = n1;
    }
    // reduce over the 16 q-cols (lane bits 0..3)
    #pragma unroll
    for (int m = 1; m < 16; m <<= 1)
        #pragma unroll
        for (int kt = 0; kt < 4; ++kt)
            #pragma unroll
            for (int r = 0; r < 4; ++r)
                z[kt][r] += __shfl_xor(z[kt][r], m, 64);
    if (llo == 0) {
        #pragma unroll
        for (int kt = 0; kt < 4; ++kt)
            *(f32x4*)(zpart + ((long)qs * 32 + b) * SS + kbase + kt * 16 + lhi * 4) = z[kt];
    }
}

// ---------------- Kernel B2: finalize wneg = -log2(sum of partials) --------
__global__ __launch_bounds__(256) void finalize_kernel(
    const float* __restrict__ zpart, float* __restrict__ wneg)
{
    int i = blockIdx.x * 256 + threadIdx.x;   // b*2048 + k, 65536 total
    float s = 0.f;
    #pragma unroll
    for (int qs = 0; qs < 8; ++qs) s += zpart[(long)qs * 32 * SS + i];
    wneg[i] = -__builtin_amdgcn_logf(s);      // v_log_f32 = log2
}

// ---------------- Kernel C: attention + output projection ----------------
// Block = 64 q-rows (4 q-frags, shared); 4 waves k-split (512 k each, 16 iters).
// Partial h1 reduced via LDS; epilogue MFMA split per wave by f-block.
__global__ __launch_bounds__(256, 4) void attn_out_kernel(
    const _Float16* __restrict__ qp, const _Float16* __restrict__ kp,
    const _Float16* __restrict__ vt, const float* __restrict__ wneg,
    const float* __restrict__ Wh, float* __restrict__ out)
{
    __shared__ float red[32][4][64];
    int w = blockIdx.x;
    int b = (w & 7) * 4 + ((w >> 3) & 3);    // same-b blocks share XCD residue
    int qblk = w >> 5;
    int t = threadIdx.x;
    int wv = t >> 6, l = t & 63, llo = l & 15, lhi = l >> 4;
    int q0 = qblk * 64;
    int kstart = wv * 512;

    const _Float16* qb = qp + ((long)b * SS + q0 + llo) * 32 + 8 * lhi;
    f16x8 qf[4];
    #pragma unroll
    for (int g = 0; g < 4; ++g) qf[g] = *(const f16x8*)(qb + g * 512);

    f32x4 acc[8];
    #pragma unroll
    for (int i = 0; i < 8; ++i) acc[i] = (f32x4){0,0,0,0};

    const float* wcb = wneg + (long)b * SS + kstart + lhi * 4;
    const _Float16* vb0 = vt + ((long)b * 32 + llo) * SS + kstart + lhi * 4;
    const _Float16* vb1 = vb0 + 16 * SS;
    const _Float16* kb = kp + ((long)b * SS + kstart + llo) * 32 + 8 * lhi;

    struct Tile {
        f16x8 kfA, kfB;
        float4 wA, wB;
        f16x4 vA0, vA1, vB0, vB1;
    };
    Tile Tb[2];
    auto load_tile = [&](Tile& T, int k0) {
        T.kfA = *(const f16x8*)(kb + (long)k0 * 32);
        T.kfB = *(const f16x8*)(kb + (long)(k0 + 16) * 32);
        T.wA  = *(const float4*)(wcb + k0);
        T.wB  = *(const float4*)(wcb + k0 + 16);
        T.vA0 = *(const f16x4*)(vb0 + k0);
        T.vA1 = *(const f16x4*)(vb1 + k0);
        T.vB0 = *(const f16x4*)(vb0 + k0 + 16);
        T.vB1 = *(const f16x4*)(vb1 + k0 + 16);
    };
    load_tile(Tb[0], 0);

    #pragma unroll 2
    for (int kt = 0; kt < 16; ++kt) {
        Tile& cur = Tb[kt & 1];
        Tile& nxt = Tb[(kt + 1) & 1];
        load_tile(nxt, ((kt + 1) & 15) * 32);

        f32x4 cA = {cur.wA.x, cur.wA.y, cur.wA.z, cur.wA.w};
        f32x4 cB = {cur.wB.x, cur.wB.y, cur.wB.z, cur.wB.w};
        f32x4 dA[4], dB[4];
        __builtin_amdgcn_s_setprio(1);
        #pragma unroll
        for (int g = 0; g < 4; ++g)
            dA[g] = __builtin_amdgcn_mfma_f32_16x16x32_f16(cur.kfA, qf[g], cA, 0, 0, 0);
        #pragma unroll
        for (int g = 0; g < 4; ++g)
            dB[g] = __builtin_amdgcn_mfma_f32_16x16x32_f16(cur.kfB, qf[g], cB, 0, 0, 0);
        __builtin_amdgcn_s_setprio(0);

        #pragma unroll
        for (int g = 0; g < 4; ++g) {
            f16x4 pA, pB;
            #pragma unroll
            for (int r = 0; r < 4; ++r) {
                pA[r] = (_Float16)__builtin_amdgcn_exp2f(dA[g][r]);
                pB[r] = (_Float16)__builtin_amdgcn_exp2f(dB[g][r]);
            }
            __builtin_amdgcn_s_setprio(1);
            acc[2*g]   = __builtin_amdgcn_mfma_f32_16x16x16f16(cur.vA0, pA, acc[2*g],   0, 0, 0);
            acc[2*g+1] = __builtin_amdgcn_mfma_f32_16x16x16f16(cur.vA1, pA, acc[2*g+1], 0, 0, 0);
            acc[2*g]   = __builtin_amdgcn_mfma_f32_16x16x16f16(cur.vB0, pB, acc[2*g],   0, 0, 0);
            acc[2*g+1] = __builtin_amdgcn_mfma_f32_16x16x16f16(cur.vB1, pB, acc[2*g+1], 0, 0, 0);
            __builtin_amdgcn_s_setprio(0);
        }
    }

    // cross-wave reduction of partial h1 (conflict-free: lane stride 1)
    #pragma unroll
    for (int i = 0; i < 8; ++i)
        #pragma unroll
        for (int r = 0; r < 4; ++r)
            red[i * 4 + r][wv][l] = acc[i][r];
    __syncthreads();

    // epilogue: wave wv produces output f-columns [wv*16, wv*16+16)
    f16x4 wlo, whi;
    #pragma unroll
    for (int j = 0; j < 4; ++j) {
        wlo[j] = (_Float16)Wh[(4 * lhi + j) * 64 + wv * 16 + llo];
        whi[j] = (_Float16)Wh[(16 + 4 * lhi + j) * 64 + wv * 16 + llo];
    }
    #pragma unroll
    for (int g = 0; g < 4; ++g) {
        f16x4 h0, h1;
        #pragma unroll
        for (int r = 0; r < 4; ++r) {
            int i0 = (2 * g) * 4 + r, i1 = (2 * g + 1) * 4 + r;
            h0[r] = (_Float16)(red[i0][0][l] + red[i0][1][l] + red[i0][2][l] + red[i0][3][l]);
            h1[r] = (_Float16)(red[i1][0][l] + red[i1][1][l] + red[i1][2][l] + red[i1][3][l]);
        }
        f32x4 o = __builtin_amdgcn_mfma_f32_16x16x16f16(wlo, h0, (f32x4){0,0,0,0}, 0, 0, 0);
        o = __builtin_amdgcn_mfma_f32_16x16x16f16(whi, h1, o, 0, 0, 0);
        *(f32x4*)(out + ((long)b * SS + q0 + g * 16 + llo) * 64 + wv * 16 + 4 * lhi) = o;
    }
}

extern "C" void kernel_launch(void* const* d_in, const int* in_sizes, int n_in,
                              void* d_out, int out_size, void* d_ws, size_t ws_size,
                              hipStream_t stream) {
    const float* x  = (const float*)d_in[0];
    const float* Wq = (const float*)d_in[1];
    const float* Wk = (const float*)d_in[2];
    const float* Wv = (const float*)d_in[3];
    const float* Wh = (const float*)d_in[4];
    float* out = (float*)d_out;

    char* ws = (char*)d_ws;
    _Float16* qp  = (_Float16*)(ws);                          // 4 MB
    _Float16* kp  = (_Float16*)(ws + (4l << 20));             // 4 MB
    _Float16* vt  = (_Float16*)(ws + (8l << 20));             // 4 MB
    float* wneg   = (float*)(ws + (12l << 20));               // 256 KB
    float* zpart  = (float*)(ws + (12l << 20) + (256l << 10)); // 2 MB

    qkv_kernel<<<1024, 256, 0, stream>>>(x, Wq, Wk, Wv, qp, kp, vt);
    stats_kernel<<<2048, 256, 0, stream>>>(qp, kp, zpart);
    finalize_kernel<<<256, 256, 0, stream>>>(zpart, wneg);
    attn_out_kernel<<<1024, 256, 0, stream>>>(qp, kp, vt, wneg, Wh, out);
}

// Round 5
// 105.945 us; speedup vs baseline: 2.3191x; 1.0540x over previous
//
#include <hip/hip_runtime.h>
#include <hip/hip_fp16.h>

#define SS 2048
#define L2E 1.44269504088896340736f

typedef _Float16 f16x4 __attribute__((ext_vector_type(4)));
typedef _Float16 f16x8 __attribute__((ext_vector_type(8)));
typedef float f32x4 __attribute__((ext_vector_type(4)));

#define GLDS16(g, l) __builtin_amdgcn_global_load_lds(                          \
    (const __attribute__((address_space(1))) void*)(g),                         \
    (__attribute__((address_space(3))) void*)(l), 16, 0, 0)
#define GLDS4(g, l) __builtin_amdgcn_global_load_lds(                           \
    (const __attribute__((address_space(1))) void*)(g),                         \
    (__attribute__((address_space(3))) void*)(l), 4, 0, 0)

// ---------------- Kernel A: QKV projection ----------------
// Outputs in MFMA-fragment-contiguous layouts:
//  qf/kf: [b][tile=s/16][ (feat/8)*16 + s%16 ][8 f16]   (1KB per 16-row tile)
//         q pre-scaled by log2e; feats 24..31 are zero.
//  vf:    [b][k/64][ (k/16)&3 ][vd/16][ ((k/4)&3)*16 + vd%16 ][4 f16]
__global__ __launch_bounds__(256) void qkv_kernel(
    const float* __restrict__ x, const float* __restrict__ Wq,
    const float* __restrict__ Wk, const float* __restrict__ Wv,
    _Float16* __restrict__ qfp, _Float16* __restrict__ kfp,
    _Float16* __restrict__ vfp)
{
    __shared__ float xs[64 * 65];
    __shared__ float wc[64 * 96];

    int t = threadIdx.x;
    for (int i = t; i < 64 * 96; i += 256) {
        int f = i / 96, c = i % 96;
        float v = 0.f;
        if (c < 24) v = Wq[f * 24 + c];
        else if (c >= 32 && c < 56) v = Wk[f * 24 + (c - 32)];
        else if (c >= 64) v = Wv[f * 32 + (c - 64)];
        wc[i] = v;
    }
    long rowbase = (long)blockIdx.x * 64;
    const float4* xg = (const float4*)(x + rowbase * 64);
    for (int i = t; i < 64 * 16; i += 256) {
        int r = i >> 4, c4 = i & 15;
        float4 v = xg[i];
        xs[r * 65 + c4 * 4 + 0] = v.x;
        xs[r * 65 + c4 * 4 + 1] = v.y;
        xs[r * 65 + c4 * 4 + 2] = v.z;
        xs[r * 65 + c4 * 4 + 3] = v.w;
    }
    __syncthreads();

    int rg = t >> 4;
    int cg = t & 15;
    float acc[4][6];
    #pragma unroll
    for (int j = 0; j < 4; ++j)
        #pragma unroll
        for (int i = 0; i < 6; ++i) acc[j][i] = 0.f;

    #pragma unroll 8
    for (int f = 0; f < 64; ++f) {
        float xv[4];
        #pragma unroll
        for (int j = 0; j < 4; ++j) xv[j] = xs[(rg * 4 + j) * 65 + f];
        #pragma unroll
        for (int i = 0; i < 6; ++i) {
            float w = wc[f * 96 + cg * 6 + i];
            #pragma unroll
            for (int j = 0; j < 4; ++j) acc[j][i] += xv[j] * w;
        }
    }

    #pragma unroll
    for (int j = 0; j < 4; ++j) {
        long R = rowbase + rg * 4 + j;
        int b = (int)(R >> 11), s = (int)(R & 2047);
        int st = s >> 4, sl = s & 15;
        #pragma unroll
        for (int i = 0; i < 6; ++i) {
            int c = cg * 6 + i;
            float a = acc[j][i];
            if (c < 32) {
                qfp[((long)b * 128 + st) * 512 + ((c >> 3) * 16 + sl) * 8 + (c & 7)]
                    = (_Float16)(a * L2E);
            } else if (c < 64) {
                int cc = c - 32;
                kfp[((long)b * 128 + st) * 512 + ((cc >> 3) * 16 + sl) * 8 + (cc & 7)]
                    = (_Float16)a;
            } else {
                int vd = c - 64;
                vfp[((long)b * 32 + (s >> 6)) * 2048 + ((s >> 4) & 3) * 512
                    + (vd >> 4) * 256 + (((s >> 2) & 3) * 16 + (vd & 15)) * 4 + (s & 3)]
                    = (_Float16)a;
            }
        }
    }
}

// ---------------- Kernel B: partial column-softmax sums ----------------
// Wave owns 64 k (4 hoisted K-frags), streams 256 q (16 contiguous 1KB frags).
__global__ __launch_bounds__(256) void stats_kernel(
    const _Float16* __restrict__ qf, const _Float16* __restrict__ kf,
    float* __restrict__ zpart)
{
    int w = blockIdx.x;
    int b = w & 31, kb = (w >> 5) & 7, qs = w >> 8;
    int t = threadIdx.x;
    int wv = t >> 6, l = t & 63, llo = l & 15, lhi = l >> 4;

    const _Float16* kfb = kf + ((long)b * 128 + kb * 16 + wv * 4) * 512 + l * 8;
    f16x8 af[4];
    #pragma unroll
    for (int kt = 0; kt < 4; ++kt) af[kt] = *(const f16x8*)(kfb + kt * 512);

    const _Float16* qb = qf + ((long)b * 128 + qs * 16) * 512 + l * 8;
    f32x4 z[4] = {{0,0,0,0},{0,0,0,0},{0,0,0,0},{0,0,0,0}};

    #pragma unroll 4
    for (int qi = 0; qi < 16; ++qi) {
        f16x8 q0 = *(const f16x8*)(qb + qi * 512);
        #pragma unroll
        for (int kt = 0; kt < 4; ++kt) {
            f32x4 d = __builtin_amdgcn_mfma_f32_16x16x32_f16(af[kt], q0,
                        (f32x4){0,0,0,0}, 0, 0, 0);
            #pragma unroll
            for (int r = 0; r < 4; ++r) z[kt][r] += __builtin_amdgcn_exp2f(d[r]);
        }
    }
    #pragma unroll
    for (int m = 1; m < 16; m <<= 1)
        #pragma unroll
        for (int kt = 0; kt < 4; ++kt)
            #pragma unroll
            for (int r = 0; r < 4; ++r) z[kt][r] += __shfl_xor(z[kt][r], m, 64);
    if (llo == 0) {
        #pragma unroll
        for (int kt = 0; kt < 4; ++kt)
            *(f32x4*)(zpart + ((long)qs * 32 + b) * SS + kb * 256 + wv * 64
                      + kt * 16 + lhi * 4) = z[kt];
    }
}

// ---------------- Kernel B2: finalize wneg = -log2(sum of partials) --------
__global__ __launch_bounds__(256) void finalize_kernel(
    const float* __restrict__ zpart, float* __restrict__ wneg)
{
    int i = blockIdx.x * 256 + threadIdx.x;
    float s = 0.f;
    #pragma unroll
    for (int qs = 0; qs < 8; ++qs) s += zpart[(long)qs * 32 * SS + i];
    wneg[i] = -__builtin_amdgcn_logf(s);
}

// ---------------- Kernel C: attention + output projection ----------------
// 4 waves split q (16 rows each, private accs); shared double-buffered LDS
// K/V/w tiles (64 k) staged via global_load_lds; one barrier per tile.
__global__ __launch_bounds__(256) void attn_out_kernel(
    const _Float16* __restrict__ qf, const _Float16* __restrict__ kf,
    const _Float16* __restrict__ vf, const float* __restrict__ wneg,
    const float* __restrict__ Wh, float* __restrict__ out)
{
    __shared__ __align__(16) _Float16 lds[2][4224];  // per buf: K 2048 | V 2048 | w 64 f32

    int w = blockIdx.x;
    int b = w & 31, qblk = w >> 5;
    int t = threadIdx.x;
    int wv = t >> 6, l = t & 63, llo = l & 15, lhi = l >> 4;
    int q0 = qblk * 64 + wv * 16;

    f16x8 qfr = *(const f16x8*)(qf + ((long)b * 128 + qblk * 4 + wv) * 512 + l * 8);

    f16x4 whlo[4], whhi[4];
    #pragma unroll
    for (int fb = 0; fb < 4; ++fb)
        #pragma unroll
        for (int j = 0; j < 4; ++j) {
            whlo[fb][j] = (_Float16)Wh[(4 * lhi + j) * 64 + fb * 16 + llo];
            whhi[fb][j] = (_Float16)Wh[(16 + 4 * lhi + j) * 64 + fb * 16 + llo];
        }

    const _Float16* kgb = kf + ((long)b * 128 + wv) * 512 + l * 8;       // + tile*2048
    const _Float16* vgb = vf + ((long)b * 32) * 2048 + wv * 512 + l * 8; // + tile*2048
    const float*    wgb = wneg + (long)b * SS + l;                        // + tile*64

    f32x4 acc0 = {0,0,0,0}, acc1 = {0,0,0,0};

    // prologue stage tile 0 into buf 0
    GLDS16(kgb, &lds[0][wv * 512]);
    GLDS16(vgb, &lds[0][2048 + wv * 512]);
    if (wv == 0) GLDS4(wgb, (float*)&lds[0][4096]);

    for (int tile = 0; tile < 32; ++tile) {
        int cb = tile & 1;
        __syncthreads();   // own-stage drained at barrier entry -> lds[cb] ready
        if (tile < 31) {   // stage next tile; flight overlaps compute below
            GLDS16(kgb + (long)(tile + 1) * 2048, &lds[cb ^ 1][wv * 512]);
            GLDS16(vgb + (long)(tile + 1) * 2048, &lds[cb ^ 1][2048 + wv * 512]);
            if (wv == 0) GLDS4(wgb + (tile + 1) * 64, (float*)&lds[cb ^ 1][4096]);
        }
        const _Float16* Kb = &lds[cb][0];
        const _Float16* Vb = &lds[cb][2048];
        const float*    Wb = (const float*)&lds[cb][4096];
        #pragma unroll
        for (int t4 = 0; t4 < 4; ++t4) {
            f16x8 kfr = *(const f16x8*)(Kb + t4 * 512 + l * 8);
            float4 w4 = *(const float4*)(Wb + t4 * 16 + lhi * 4);
            f32x4 d = __builtin_amdgcn_mfma_f32_16x16x32_f16(kfr, qfr,
                        (f32x4){w4.x, w4.y, w4.z, w4.w}, 0, 0, 0);
            f16x4 pa;
            #pragma unroll
            for (int r = 0; r < 4; ++r) pa[r] = (_Float16)__builtin_amdgcn_exp2f(d[r]);
            f16x4 v0 = *(const f16x4*)(Vb + t4 * 512 + l * 4);
            f16x4 v1 = *(const f16x4*)(Vb + t4 * 512 + 256 + l * 4);
            acc0 = __builtin_amdgcn_mfma_f32_16x16x16f16(v0, pa, acc0, 0, 0, 0);
            acc1 = __builtin_amdgcn_mfma_f32_16x16x16f16(v1, pa, acc1, 0, 0, 0);
        }
    }

    // epilogue: O^T = Wh^T * h1^T via MFMA; accs are already B-fragments.
    f16x4 h0, h1;
    #pragma unroll
    for (int r = 0; r < 4; ++r) {
        h0[r] = (_Float16)acc0[r];
        h1[r] = (_Float16)acc1[r];
    }
    float* orow = out + ((long)b * SS + q0 + llo) * 64 + 4 * lhi;
    #pragma unroll
    for (int fb = 0; fb < 4; ++fb) {
        f32x4 o = __builtin_amdgcn_mfma_f32_16x16x16f16(whlo[fb], h0,
                    (f32x4){0,0,0,0}, 0, 0, 0);
        o = __builtin_amdgcn_mfma_f32_16x16x16f16(whhi[fb], h1, o, 0, 0, 0);
        *(f32x4*)(orow + fb * 16) = o;
    }
}

extern "C" void kernel_launch(void* const* d_in, const int* in_sizes, int n_in,
                              void* d_out, int out_size, void* d_ws, size_t ws_size,
                              hipStream_t stream) {
    const float* x  = (const float*)d_in[0];
    const float* Wq = (const float*)d_in[1];
    const float* Wk = (const float*)d_in[2];
    const float* Wv = (const float*)d_in[3];
    const float* Wh = (const float*)d_in[4];
    float* out = (float*)d_out;

    char* ws = (char*)d_ws;
    _Float16* qf  = (_Float16*)(ws);                           // 4 MB
    _Float16* kf  = (_Float16*)(ws + (4l << 20));              // 4 MB
    _Float16* vf  = (_Float16*)(ws + (8l << 20));              // 4 MB
    float* wneg   = (float*)(ws + (12l << 20));                // 256 KB
    float* zpart  = (float*)(ws + (12l << 20) + (256l << 10)); // 2 MB

    qkv_kernel<<<1024, 256, 0, stream>>>(x, Wq, Wk, Wv, qf, kf, vf);
    stats_kernel<<<2048, 256, 0, stream>>>(qf, kf, zpart);
    finalize_kernel<<<256, 256, 0, stream>>>(zpart, wneg);
    attn_out_kernel<<<1024, 256, 0, stream>>>(qf, kf, vf, wneg, Wh, out);
}

// Round 6
// 83.823 us; speedup vs baseline: 2.9311x; 1.2639x over previous
//
#include <hip/hip_runtime.h>
#include <hip/hip_fp16.h>

#define SS 2048
#define L2E 1.44269504088896340736f

typedef _Float16 f16x4 __attribute__((ext_vector_type(4)));
typedef _Float16 f16x8 __attribute__((ext_vector_type(8)));
typedef float f32x4 __attribute__((ext_vector_type(4)));

#define GLDS16(g, l) __builtin_amdgcn_global_load_lds(                          \
    (const __attribute__((address_space(1))) void*)(g),                         \
    (__attribute__((address_space(3))) void*)(l), 16, 0, 0)
#define GLDS4(g, l) __builtin_amdgcn_global_load_lds(                           \
    (const __attribute__((address_space(1))) void*)(g),                         \
    (__attribute__((address_space(3))) void*)(l), 4, 0, 0)

// ---------------- Kernel A: QKV projection ----------------
// Fragment-contiguous outputs (same layouts as round 5):
//  qf/kf: [b][tile=s/16][ (feat/8)*16 + s%16 ][8 f16]; q pre-scaled by log2e;
//         feats 24..31 zero.
//  vf:    [b][s/64][ (s/16)&3 ][vd/16][ ((s/4)&3)*16 + vd%16 ][4 f16]
// Compute with register blocking, scatter into LDS staging (byte-identical to
// the global fragment stream), then 3x coalesced 16B/lane stores.
__global__ __launch_bounds__(256) void qkv_kernel(
    const float* __restrict__ x, const float* __restrict__ Wq,
    const float* __restrict__ Wk, const float* __restrict__ Wv,
    _Float16* __restrict__ qfp, _Float16* __restrict__ kfp,
    _Float16* __restrict__ vfp)
{
    __shared__ float xs[64 * 65];          // 16.6 KB
    __shared__ float wc[64 * 80];          // 20 KB: cols q24 | k24 | v32
    __shared__ __align__(16) _Float16 os[3 * 2048];  // 12 KB: q | k | v fragment regions

    int t = threadIdx.x;
    // stage weights
    for (int i = t; i < 64 * 80; i += 256) {
        int f = i / 80, c = i % 80;
        float v;
        if (c < 24) v = Wq[f * 24 + c];
        else if (c < 48) v = Wk[f * 24 + (c - 24)];
        else v = Wv[f * 32 + (c - 48)];
        wc[i] = v;
    }
    // stage x tile (64 rows x 64 f32)
    long rowbase = (long)blockIdx.x * 64;
    const float4* xg = (const float4*)(x + rowbase * 64);
    for (int i = t; i < 64 * 16; i += 256) {
        int r = i >> 4, c4 = i & 15;
        float4 v = xg[i];
        xs[r * 65 + c4 * 4 + 0] = v.x;
        xs[r * 65 + c4 * 4 + 1] = v.y;
        xs[r * 65 + c4 * 4 + 2] = v.z;
        xs[r * 65 + c4 * 4 + 3] = v.w;
    }
    // zero pad-groups (feat group 3) of q and k fragment regions
    if (t < 128) {
        int reg = t >> 6, rr = t & 63;
        *(f16x8*)&os[reg * 2048 + (rr >> 4) * 512 + (48 + (rr & 15)) * 8]
            = (f16x8){0, 0, 0, 0, 0, 0, 0, 0};
    }
    __syncthreads();

    int rg = t >> 4;   // 16 row-groups of 4 rows
    int cg = t & 15;   // 16 col-groups of 5 cols
    float acc[4][5];
    #pragma unroll
    for (int j = 0; j < 4; ++j)
        #pragma unroll
        for (int i = 0; i < 5; ++i) acc[j][i] = 0.f;

    #pragma unroll 8
    for (int f = 0; f < 64; ++f) {
        float xv[4];
        #pragma unroll
        for (int j = 0; j < 4; ++j) xv[j] = xs[(rg * 4 + j) * 65 + f];
        #pragma unroll
        for (int i = 0; i < 5; ++i) {
            float w = wc[f * 80 + cg * 5 + i];
            #pragma unroll
            for (int j = 0; j < 4; ++j) acc[j][i] += xv[j] * w;
        }
    }

    // scatter acc -> os in fragment layout (LDS absorbs the scatter)
    int st_l = rg >> 2;            // local 16-row tile (0..3)
    int slb  = (rg & 3) * 4;       // row-within-tile base
    #pragma unroll
    for (int j = 0; j < 4; ++j) {
        int sl = slb + j;
        #pragma unroll
        for (int i = 0; i < 5; ++i) {
            int c = cg * 5 + i;
            if (c < 24) {
                os[st_l * 512 + ((c >> 3) * 16 + sl) * 8 + (c & 7)]
                    = (_Float16)(acc[j][i] * L2E);
            } else if (c < 48) {
                int ck = c - 24;
                os[2048 + st_l * 512 + ((ck >> 3) * 16 + sl) * 8 + (ck & 7)]
                    = (_Float16)acc[j][i];
            } else {
                int vd = c - 48;
                os[4096 + st_l * 512 + (vd >> 4) * 256
                   + ((rg & 3) * 16 + (vd & 15)) * 4 + j] = (_Float16)acc[j][i];
            }
        }
    }
    __syncthreads();

    // coalesced store-out: each region is a contiguous 4KB chunk per block
    long blk = blockIdx.x;
    *(f16x8*)(qfp + blk * 2048 + t * 8) = *(const f16x8*)&os[t * 8];
    *(f16x8*)(kfp + blk * 2048 + t * 8) = *(const f16x8*)&os[2048 + t * 8];
    *(f16x8*)(vfp + blk * 2048 + t * 8) = *(const f16x8*)&os[4096 + t * 8];
}

// ---------------- Kernel B: partial column-softmax sums ----------------
// Wave owns 64 k (4 hoisted K-frags), streams 256 q (16 contiguous 1KB frags).
__global__ __launch_bounds__(256) void stats_kernel(
    const _Float16* __restrict__ qf, const _Float16* __restrict__ kf,
    float* __restrict__ zpart)
{
    int w = blockIdx.x;
    int b = w & 31, kb = (w >> 5) & 7, qs = w >> 8;
    int t = threadIdx.x;
    int wv = t >> 6, l = t & 63, llo = l & 15, lhi = l >> 4;

    const _Float16* kfb = kf + ((long)b * 128 + kb * 16 + wv * 4) * 512 + l * 8;
    f16x8 af[4];
    #pragma unroll
    for (int kt = 0; kt < 4; ++kt) af[kt] = *(const f16x8*)(kfb + kt * 512);

    const _Float16* qb = qf + ((long)b * 128 + qs * 16) * 512 + l * 8;
    f32x4 z[4] = {{0,0,0,0},{0,0,0,0},{0,0,0,0},{0,0,0,0}};

    #pragma unroll 4
    for (int qi = 0; qi < 16; ++qi) {
        f16x8 q0 = *(const f16x8*)(qb + qi * 512);
        #pragma unroll
        for (int kt = 0; kt < 4; ++kt) {
            f32x4 d = __builtin_amdgcn_mfma_f32_16x16x32_f16(af[kt], q0,
                        (f32x4){0,0,0,0}, 0, 0, 0);
            #pragma unroll
            for (int r = 0; r < 4; ++r) z[kt][r] += __builtin_amdgcn_exp2f(d[r]);
        }
    }
    #pragma unroll
    for (int m = 1; m < 16; m <<= 1)
        #pragma unroll
        for (int kt = 0; kt < 4; ++kt)
            #pragma unroll
            for (int r = 0; r < 4; ++r) z[kt][r] += __shfl_xor(z[kt][r], m, 64);
    if (llo == 0) {
        #pragma unroll
        for (int kt = 0; kt < 4; ++kt)
            *(f32x4*)(zpart + ((long)qs * 32 + b) * SS + kb * 256 + wv * 64
                      + kt * 16 + lhi * 4) = z[kt];
    }
}

// ---------------- Kernel B2: finalize wneg = -log2(sum of partials) --------
__global__ __launch_bounds__(256) void finalize_kernel(
    const float* __restrict__ zpart, float* __restrict__ wneg)
{
    int i = blockIdx.x * 256 + threadIdx.x;
    float s = 0.f;
    #pragma unroll
    for (int qs = 0; qs < 8; ++qs) s += zpart[(long)qs * 32 * SS + i];
    wneg[i] = -__builtin_amdgcn_logf(s);
}

// ---------------- Kernel C: attention + output projection ----------------
// 4 waves split q (16 rows each, private accs); shared double-buffered LDS
// K/V/w tiles (64 k) staged via global_load_lds; one barrier per tile.
__global__ __launch_bounds__(256) void attn_out_kernel(
    const _Float16* __restrict__ qf, const _Float16* __restrict__ kf,
    const _Float16* __restrict__ vf, const float* __restrict__ wneg,
    const float* __restrict__ Wh, float* __restrict__ out)
{
    __shared__ __align__(16) _Float16 lds[2][4224];  // per buf: K 2048 | V 2048 | w 64 f32

    int w = blockIdx.x;
    int b = w & 31, qblk = w >> 5;
    int t = threadIdx.x;
    int wv = t >> 6, l = t & 63, llo = l & 15, lhi = l >> 4;
    int q0 = qblk * 64 + wv * 16;

    f16x8 qfr = *(const f16x8*)(qf + ((long)b * 128 + qblk * 4 + wv) * 512 + l * 8);

    f16x4 whlo[4], whhi[4];
    #pragma unroll
    for (int fb = 0; fb < 4; ++fb)
        #pragma unroll
        for (int j = 0; j < 4; ++j) {
            whlo[fb][j] = (_Float16)Wh[(4 * lhi + j) * 64 + fb * 16 + llo];
            whhi[fb][j] = (_Float16)Wh[(16 + 4 * lhi + j) * 64 + fb * 16 + llo];
        }

    const _Float16* kgb = kf + ((long)b * 128 + wv) * 512 + l * 8;       // + tile*2048
    const _Float16* vgb = vf + ((long)b * 32) * 2048 + wv * 512 + l * 8; // + tile*2048
    const float*    wgb = wneg + (long)b * SS + l;                        // + tile*64

    f32x4 acc0 = {0,0,0,0}, acc1 = {0,0,0,0};

    // prologue stage tile 0 into buf 0
    GLDS16(kgb, &lds[0][wv * 512]);
    GLDS16(vgb, &lds[0][2048 + wv * 512]);
    if (wv == 0) GLDS4(wgb, (float*)&lds[0][4096]);

    for (int tile = 0; tile < 32; ++tile) {
        int cb = tile & 1;
        __syncthreads();   // own-stage drained at barrier entry -> lds[cb] ready
        if (tile < 31) {   // stage next tile; flight overlaps compute below
            GLDS16(kgb + (long)(tile + 1) * 2048, &lds[cb ^ 1][wv * 512]);
            GLDS16(vgb + (long)(tile + 1) * 2048, &lds[cb ^ 1][2048 + wv * 512]);
            if (wv == 0) GLDS4(wgb + (tile + 1) * 64, (float*)&lds[cb ^ 1][4096]);
        }
        const _Float16* Kb = &lds[cb][0];
        const _Float16* Vb = &lds[cb][2048];
        const float*    Wb = (const float*)&lds[cb][4096];
        #pragma unroll
        for (int t4 = 0; t4 < 4; ++t4) {
            f16x8 kfr = *(const f16x8*)(Kb + t4 * 512 + l * 8);
            float4 w4 = *(const float4*)(Wb + t4 * 16 + lhi * 4);
            f32x4 d = __builtin_amdgcn_mfma_f32_16x16x32_f16(kfr, qfr,
                        (f32x4){w4.x, w4.y, w4.z, w4.w}, 0, 0, 0);
            f16x4 pa;
            #pragma unroll
            for (int r = 0; r < 4; ++r) pa[r] = (_Float16)__builtin_amdgcn_exp2f(d[r]);
            f16x4 v0 = *(const f16x4*)(Vb + t4 * 512 + l * 4);
            f16x4 v1 = *(const f16x4*)(Vb + t4 * 512 + 256 + l * 4);
            acc0 = __builtin_amdgcn_mfma_f32_16x16x16f16(v0, pa, acc0, 0, 0, 0);
            acc1 = __builtin_amdgcn_mfma_f32_16x16x16f16(v1, pa, acc1, 0, 0, 0);
        }
    }

    // epilogue: O^T = Wh^T * h1^T via MFMA; accs are already B-fragments.
    f16x4 h0, h1;
    #pragma unroll
    for (int r = 0; r < 4; ++r) {
        h0[r] = (_Float16)acc0[r];
        h1[r] = (_Float16)acc1[r];
    }
    float* orow = out + ((long)b * SS + q0 + llo) * 64 + 4 * lhi;
    #pragma unroll
    for (int fb = 0; fb < 4; ++fb) {
        f32x4 o = __builtin_amdgcn_mfma_f32_16x16x16f16(whlo[fb], h0,
                    (f32x4){0,0,0,0}, 0, 0, 0);
        o = __builtin_amdgcn_mfma_f32_16x16x16f16(whhi[fb], h1, o, 0, 0, 0);
        *(f32x4*)(orow + fb * 16) = o;
    }
}

extern "C" void kernel_launch(void* const* d_in, const int* in_sizes, int n_in,
                              void* d_out, int out_size, void* d_ws, size_t ws_size,
                              hipStream_t stream) {
    const float* x  = (const float*)d_in[0];
    const float* Wq = (const float*)d_in[1];
    const float* Wk = (const float*)d_in[2];
    const float* Wv = (const float*)d_in[3];
    const float* Wh = (const float*)d_in[4];
    float* out = (float*)d_out;

    char* ws = (char*)d_ws;
    _Float16* qf  = (_Float16*)(ws);                           // 4 MB
    _Float16* kf  = (_Float16*)(ws + (4l << 20));              // 4 MB
    _Float16* vf  = (_Float16*)(ws + (8l << 20));              // 4 MB
    float* wneg   = (float*)(ws + (12l << 20));                // 256 KB
    float* zpart  = (float*)(ws + (12l << 20) + (256l << 10)); // 2 MB

    qkv_kernel<<<1024, 256, 0, stream>>>(x, Wq, Wk, Wv, qf, kf, vf);
    stats_kernel<<<2048, 256, 0, stream>>>(qf, kf, zpart);
    finalize_kernel<<<256, 256, 0, stream>>>(zpart, wneg);
    attn_out_kernel<<<1024, 256, 0, stream>>>(qf, kf, vf, wneg, Wh, out);
}